// Round 8
// baseline (580.691 us; speedup 1.0000x reference)
//
#include <hip/hip_runtime.h>

#define N_NODES 100000
#define N_EDGES 600000
#define N_GRAPHS 2000
#define DIM 128
#define HIDDEN 256
#define N_CONV 4
#define NB_SCAN ((N_NODES + 255) / 256)   // 391

typedef short s16x8 __attribute__((ext_vector_type(8)));
typedef float f32x4 __attribute__((ext_vector_type(4)));

// ---------------- CSR build ----------------

__global__ __launch_bounds__(256) void k_hist(const int* __restrict__ ei, int* __restrict__ cnt) {
    int e = blockIdx.x * 256 + threadIdx.x;
    if (e < N_EDGES) atomicAdd(&cnt[ei[N_EDGES + e]], 1);
}

__global__ __launch_bounds__(256) void k_dis(const int* __restrict__ cnt, float* __restrict__ dis) {
    int i = blockIdx.x * 256 + threadIdx.x;
    if (i < N_NODES) dis[i] = rsqrtf(1.0f + (float)cnt[i]);
}

__global__ __launch_bounds__(256) void k_scan1(const int* __restrict__ cnt,
                                               int* __restrict__ rp,
                                               int* __restrict__ part) {
    __shared__ int s[256];
    int t = threadIdx.x;
    int i = blockIdx.x * 256 + t;
    int v = (i < N_NODES) ? cnt[i] : 0;
    s[t] = v;
    __syncthreads();
    for (int o = 1; o < 256; o <<= 1) {
        int x = (t >= o) ? s[t - o] : 0;
        __syncthreads();
        s[t] += x;
        __syncthreads();
    }
    if (i < N_NODES) rp[i] = s[t] - v;
    if (t == 255) part[blockIdx.x] = s[255];
}

__global__ __launch_bounds__(512) void k_scan2(int* __restrict__ part) {
    __shared__ int s[512];
    int t = threadIdx.x;
    int v = (t < NB_SCAN) ? part[t] : 0;
    s[t] = v;
    __syncthreads();
    for (int o = 1; o < 512; o <<= 1) {
        int x = (t >= o) ? s[t - o] : 0;
        __syncthreads();
        s[t] += x;
        __syncthreads();
    }
    if (t < NB_SCAN) part[t] = s[t] - v;
}

__global__ __launch_bounds__(256) void k_scan3(int* __restrict__ rp, const int* __restrict__ part) {
    int i = blockIdx.x * 256 + threadIdx.x;
    if (i < N_NODES) rp[i] += part[i >> 8];
    if (i == 0) rp[N_NODES] = N_EDGES;
}

__global__ __launch_bounds__(256) void k_fill(const int* __restrict__ ei,
                                              const int* __restrict__ rp,
                                              const float* __restrict__ dis,
                                              int* __restrict__ cursor,
                                              int* __restrict__ src_csr,
                                              float* __restrict__ norm_csr) {
    int e = blockIdx.x * 256 + threadIdx.x;
    if (e < N_EDGES) {
        int s = ei[e];
        int d = ei[N_EDGES + e];
        int pos = rp[d] + atomicAdd(&cursor[d], 1);
        src_csr[pos] = s;
        norm_csr[pos] = dis[s] * dis[d];
    }
}

// ---------------- graph row pointers from sorted batch ----------------

__global__ __launch_bounds__(256) void k_grp(const int* __restrict__ batch, int* __restrict__ grp) {
    int g = blockIdx.x * 256 + threadIdx.x;
    if (g > N_GRAPHS) return;
    if (g == N_GRAPHS) { grp[g] = N_NODES; return; }
    int lo = 0, hi = N_NODES;
    while (lo < hi) {
        int mid = (lo + hi) >> 1;
        if (batch[mid] < g) lo = mid + 1; else hi = mid;
    }
    grp[g] = lo;
}

// ---------------- W split: WhT/WlT[n][k] bf16 (transposed, truncation split) ----------------

__global__ __launch_bounds__(256) void k_wsplit(const float* __restrict__ W,
                                                unsigned short* __restrict__ WhT,
                                                unsigned short* __restrict__ WlT) {
    int idx = blockIdx.x * 256 + threadIdx.x;   // layer*16384 + k*128 + n
    if (idx >= N_CONV * DIM * DIM) return;
    int layer = idx >> 14;
    int rem = idx & 16383;
    int k = rem >> 7;
    int n = rem & 127;
    float f = W[idx];
    unsigned int u = __float_as_uint(f);
    unsigned int h = u & 0xFFFF0000u;
    float lo = f - __uint_as_float(h);
    int dst = (layer << 14) | (n << 7) | k;
    WhT[dst] = (unsigned short)(h >> 16);
    WlT[dst] = (unsigned short)(__float_as_uint(lo) >> 16);
}

// ---------------- fused layer: out = relu( (S h) W + b ) ----------------
// Uses linearity: segment_sum(hW * norm) == (segment_sum(h * norm)) W.
// Block: 256 thr, 64 nodes. Phase 1: 8 groups x 32 lanes gather agg rows -> LDS.
// Phase 2: 4 waves x one 16-row m-tile; bf16x3 in-register split of agg;
// W^T (bf16 h+l planes) staged per-32-k chunk, XOR-swizzled. Epilogue: bias+relu.
// Frag layouts (HW-verified rounds 5/6): A row=l&15, k=8*(l>>4)+j; D col=l&15, row=(l>>4)*4+r.

__global__ __launch_bounds__(256, 3) void k_layer(const float* __restrict__ Hin,
                                                  const int* __restrict__ rp,
                                                  const int* __restrict__ src_csr,
                                                  const float* __restrict__ norm_csr,
                                                  const float* __restrict__ dis,
                                                  const unsigned short* __restrict__ WhT,
                                                  const unsigned short* __restrict__ WlT,
                                                  const float* __restrict__ bias,
                                                  float* __restrict__ Hout) {
    __shared__ float AG[64][132];              // 33.8 KB (pad 132 -> conflict-free frag reads)
    __shared__ unsigned short WC[2][4096];     // 16 KB: [h|l] x [n=128][k=32] swizzled chunk

    int t = threadIdx.x;
    int nbase = blockIdx.x * 64;

    // ---- phase 1: gather ----
    {
        int slot = t >> 5;
        int lane = t & 31;
        const float4* hp = (const float4*)Hin;
        for (int i = 0; i < 8; ++i) {
            int v = slot * 8 + i;
            int n = nbase + v;
            if (n < N_NODES) {
                float dn = dis[n];
                float sn = dn * dn;
                float4 h0 = hp[(size_t)n * 32 + lane];
                float4 acc = make_float4(h0.x * sn, h0.y * sn, h0.z * sn, h0.w * sn);
                int beg = rp[n], end = rp[n + 1];
                int e = beg;
                for (; e + 3 < end; e += 4) {
                    int s0 = src_csr[e], s1 = src_csr[e + 1], s2 = src_csr[e + 2], s3 = src_csr[e + 3];
                    float m0 = norm_csr[e], m1 = norm_csr[e + 1], m2 = norm_csr[e + 2], m3 = norm_csr[e + 3];
                    float4 u0 = hp[(size_t)s0 * 32 + lane];
                    float4 u1 = hp[(size_t)s1 * 32 + lane];
                    float4 u2 = hp[(size_t)s2 * 32 + lane];
                    float4 u3 = hp[(size_t)s3 * 32 + lane];
                    acc.x += u0.x * m0 + u1.x * m1 + u2.x * m2 + u3.x * m3;
                    acc.y += u0.y * m0 + u1.y * m1 + u2.y * m2 + u3.y * m3;
                    acc.z += u0.z * m0 + u1.z * m1 + u2.z * m2 + u3.z * m3;
                    acc.w += u0.w * m0 + u1.w * m1 + u2.w * m2 + u3.w * m3;
                }
                for (; e < end; ++e) {
                    int s0 = src_csr[e];
                    float m0 = norm_csr[e];
                    float4 u0 = hp[(size_t)s0 * 32 + lane];
                    acc.x += u0.x * m0; acc.y += u0.y * m0;
                    acc.z += u0.z * m0; acc.w += u0.w * m0;
                }
                *(float4*)&AG[v][lane * 4] = acc;
            }
        }
    }
    __syncthreads();

    // ---- phase 2: GEMM (bf16x3) ----
    int w = t >> 6;          // wave -> m-tile (rows w*16..+15)
    int l = t & 63;
    int lr = l & 15;
    int lk = l >> 4;

    f32x4 acc[8];
#pragma unroll
    for (int nt = 0; nt < 8; ++nt) acc[nt] = (f32x4)0.0f;

#pragma unroll 1
    for (int c = 0; c < 4; ++c) {
        // stage W chunk c (both planes), XOR-swizzled
#pragma unroll
        for (int j = 0; j < 2; ++j) {
            int idx = j * 256 + t;       // 0..511
            int n = idx >> 2;            // 0..127
            int kq = idx & 3;            // 16-B chunk within 64-B row
            int sby = (n * 64 + kq * 16) ^ (((n >> 1) & 3) << 4);
            *(uint4*)((char*)WC[0] + sby) = *(const uint4*)(WhT + n * DIM + c * 32 + kq * 8);
            *(uint4*)((char*)WC[1] + sby) = *(const uint4*)(WlT + n * DIM + c * 32 + kq * 8);
        }
        __syncthreads();

        // A fragment: rows w*16+lr, k = c*32 + lk*8 .. +7, split to bf16 h/l
        const float* ap = &AG[w * 16 + lr][c * 32 + lk * 8];
        union { int i[4]; s16x8 v; } H, L;
#pragma unroll
        for (int d = 0; d < 4; ++d) {
            float a0 = ap[2 * d], a1 = ap[2 * d + 1];
            unsigned int u0 = __float_as_uint(a0), u1 = __float_as_uint(a1);
            unsigned int h0 = u0 & 0xFFFF0000u, h1 = u1 & 0xFFFF0000u;
            float lo0 = a0 - __uint_as_float(h0);
            float lo1 = a1 - __uint_as_float(h1);
            H.i[d] = (int)(h1 | (h0 >> 16));
            L.i[d] = (int)((__float_as_uint(lo1) & 0xFFFF0000u) | (__float_as_uint(lo0) >> 16));
        }
        s16x8 ah = H.v, al = L.v;

#pragma unroll
        for (int nt = 0; nt < 8; ++nt) {
            int n = nt * 16 + lr;
            int rby = (n * 64 + lk * 16) ^ (((n >> 1) & 3) << 4);
            s16x8 wh = *(const s16x8*)((char*)WC[0] + rby);
            s16x8 wl = *(const s16x8*)((char*)WC[1] + rby);
            acc[nt] = __builtin_amdgcn_mfma_f32_16x16x32_bf16(ah, wh, acc[nt], 0, 0, 0);
            acc[nt] = __builtin_amdgcn_mfma_f32_16x16x32_bf16(ah, wl, acc[nt], 0, 0, 0);
            acc[nt] = __builtin_amdgcn_mfma_f32_16x16x32_bf16(al, wh, acc[nt], 0, 0, 0);
        }
        __syncthreads();
    }

    // ---- epilogue: bias + relu + store ----
#pragma unroll
    for (int nt = 0; nt < 8; ++nt) {
        int col = nt * 16 + lr;
        float b = bias[col];
#pragma unroll
        for (int r = 0; r < 4; ++r) {
            int row = nbase + w * 16 + lk * 4 + r;
            if (row < N_NODES) Hout[(size_t)row * DIM + col] = fmaxf(acc[nt][r] + b, 0.f);
        }
    }
}

// ---------------- segmented pooling ----------------

__global__ __launch_bounds__(256) void k_pool_seg(const float4* __restrict__ A4,
                                                  const int* __restrict__ grp,
                                                  float4* __restrict__ means4) {
    __shared__ float4 s[256];
    int g = blockIdx.x;
    int t = threadIdx.x;
    int lane = t & 31;
    int slot = t >> 5;
    int beg = grp[g], end = grp[g + 1];

    float4 acc = make_float4(0.f, 0.f, 0.f, 0.f);
    for (int n = beg + slot; n < end; n += 8) {
        float4 v = A4[(size_t)n * 32 + lane];
        acc.x += v.x; acc.y += v.y; acc.z += v.z; acc.w += v.w;
    }
    s[t] = acc;
    __syncthreads();
    if (t < 32) {
        float4 a = s[t];
#pragma unroll
        for (int i = 1; i < 8; ++i) {
            float4 b = s[t + i * 32];
            a.x += b.x; a.y += b.y; a.z += b.z; a.w += b.w;
        }
        float inv = (end > beg) ? 1.0f / (float)(end - beg) : 0.0f;
        means4[g * 32 + t] = make_float4(a.x * inv, a.y * inv, a.z * inv, a.w * inv);
    }
}

// ---------------- MLP head ----------------

__global__ __launch_bounds__(256) void k_mlp(const float* __restrict__ means,
                                             const float* __restrict__ w1,
                                             const float* __restrict__ b1,
                                             const float* __restrict__ w2,
                                             const float* __restrict__ b2,
                                             float* __restrict__ out) {
    __shared__ float m[DIM];
    __shared__ float red[HIDDEN];
    int g = blockIdx.x;
    int t = threadIdx.x;
    if (t < DIM) m[t] = means[g * DIM + t];
    __syncthreads();
    float h = b1[t];
    for (int c = 0; c < DIM; ++c) h += m[c] * w1[c * HIDDEN + t];
    red[t] = fmaxf(h, 0.f) * w2[t];
    __syncthreads();
    for (int s = HIDDEN / 2; s > 0; s >>= 1) {
        if (t < s) red[t] += red[t + s];
        __syncthreads();
    }
    if (t == 0) out[g] = red[0] + b2[0];
}

// ---------------- launch ----------------

extern "C" void kernel_launch(void* const* d_in, const int* in_sizes, int n_in,
                              void* d_out, int out_size, void* d_ws, size_t ws_size,
                              hipStream_t stream) {
    const float* x      = (const float*)d_in[0];
    const float* conv_w = (const float*)d_in[1];
    const float* conv_b = (const float*)d_in[2];
    const float* w1     = (const float*)d_in[3];
    const float* b1     = (const float*)d_in[4];
    const float* w2     = (const float*)d_in[5];
    const float* b2     = (const float*)d_in[6];
    const int*   ei     = (const int*)d_in[7];
    const int*   batch  = (const int*)d_in[8];
    float* out = (float*)d_out;

    char* ws = (char*)d_ws;
    size_t off = 0;
    auto alloc = [&](size_t bytes) {
        char* p = ws + off;
        off += (bytes + 255) & ~(size_t)255;
        return p;
    };
    float* A        = (float*)alloc((size_t)N_NODES * DIM * 4);   // 51.2 MB
    float* Bb       = (float*)alloc((size_t)N_NODES * DIM * 4);   // 51.2 MB
    int*   cnt      = (int*)alloc((size_t)N_NODES * 4);
    float* dis      = (float*)alloc((size_t)N_NODES * 4);
    int*   rp       = (int*)alloc((size_t)(N_NODES + 1) * 4);
    int*   part     = (int*)alloc((size_t)NB_SCAN * 4);
    int*   src_csr  = (int*)alloc((size_t)N_EDGES * 4);
    float* norm_csr = (float*)alloc((size_t)N_EDGES * 4);
    int*   grp      = (int*)alloc((size_t)(N_GRAPHS + 1) * 4);
    float* means    = (float*)alloc((size_t)N_GRAPHS * DIM * 4);
    unsigned short* WhT = (unsigned short*)alloc((size_t)N_CONV * DIM * DIM * 2);
    unsigned short* WlT = (unsigned short*)alloc((size_t)N_CONV * DIM * DIM * 2);
    (void)ws_size; (void)in_sizes; (void)n_in; (void)out_size;

    // --- CSR build + W split (once per call) ---
    hipMemsetAsync(cnt, 0, (size_t)N_NODES * 4, stream);
    k_hist<<<(N_EDGES + 255) / 256, 256, 0, stream>>>(ei, cnt);
    k_dis<<<(N_NODES + 255) / 256, 256, 0, stream>>>(cnt, dis);
    k_scan1<<<NB_SCAN, 256, 0, stream>>>(cnt, rp, part);
    k_scan2<<<1, 512, 0, stream>>>(part);
    k_scan3<<<NB_SCAN, 256, 0, stream>>>(rp, part);
    hipMemsetAsync(cnt, 0, (size_t)N_NODES * 4, stream);
    k_fill<<<(N_EDGES + 255) / 256, 256, 0, stream>>>(ei, rp, dis, cnt, src_csr, norm_csr);
    k_grp<<<(N_GRAPHS + 256) / 256, 256, 0, stream>>>(batch, grp);
    k_wsplit<<<(N_CONV * DIM * DIM) / 256, 256, 0, stream>>>(conv_w, WhT, WlT);

    // --- conv layers (fused aggregate -> transform -> bias -> relu) ---
    const float* cur = x;
    float* dst = Bb;
    for (int L = 0; L < N_CONV; ++L) {
        k_layer<<<(N_NODES + 63) / 64, 256, 0, stream>>>(
            cur, rp, src_csr, norm_csr, dis,
            WhT + L * DIM * DIM, WlT + L * DIM * DIM, conv_b + L * DIM, dst);
        cur = dst;
        dst = (dst == Bb) ? A : Bb;
    }

    // --- pool + MLP ---
    k_pool_seg<<<N_GRAPHS, 256, 0, stream>>>((const float4*)cur, grp, (float4*)means);
    k_mlp<<<N_GRAPHS, 256, 0, stream>>>(means, w1, b1, w2, b2, out);
}

// Round 10
// 435.314 us; speedup vs baseline: 1.3340x; 1.3340x over previous
//
#include <hip/hip_runtime.h>

#define N_NODES 100000
#define N_EDGES 600000
#define N_GRAPHS 2000
#define DIM 128
#define HIDDEN 256
#define N_CONV 4
#define NB_SCAN ((N_NODES + 255) / 256)   // 391

typedef short s16x8 __attribute__((ext_vector_type(8)));
typedef float f32x4 __attribute__((ext_vector_type(4)));

// ---------------- CSR build ----------------

__global__ __launch_bounds__(256) void k_hist(const int* __restrict__ ei, int* __restrict__ cnt) {
    int e = blockIdx.x * 256 + threadIdx.x;
    if (e < N_EDGES) atomicAdd(&cnt[ei[N_EDGES + e]], 1);
}

__global__ __launch_bounds__(256) void k_dis(const int* __restrict__ cnt, float* __restrict__ dis) {
    int i = blockIdx.x * 256 + threadIdx.x;
    if (i < N_NODES) dis[i] = rsqrtf(1.0f + (float)cnt[i]);
}

__global__ __launch_bounds__(256) void k_scan1(const int* __restrict__ cnt,
                                               int* __restrict__ rp,
                                               int* __restrict__ part) {
    __shared__ int s[256];
    int t = threadIdx.x;
    int i = blockIdx.x * 256 + t;
    int v = (i < N_NODES) ? cnt[i] : 0;
    s[t] = v;
    __syncthreads();
    for (int o = 1; o < 256; o <<= 1) {
        int x = (t >= o) ? s[t - o] : 0;
        __syncthreads();
        s[t] += x;
        __syncthreads();
    }
    if (i < N_NODES) rp[i] = s[t] - v;
    if (t == 255) part[blockIdx.x] = s[255];
}

__global__ __launch_bounds__(512) void k_scan2(int* __restrict__ part) {
    __shared__ int s[512];
    int t = threadIdx.x;
    int v = (t < NB_SCAN) ? part[t] : 0;
    s[t] = v;
    __syncthreads();
    for (int o = 1; o < 512; o <<= 1) {
        int x = (t >= o) ? s[t - o] : 0;
        __syncthreads();
        s[t] += x;
        __syncthreads();
    }
    if (t < NB_SCAN) part[t] = s[t] - v;
}

__global__ __launch_bounds__(256) void k_scan3(int* __restrict__ rp, const int* __restrict__ part) {
    int i = blockIdx.x * 256 + threadIdx.x;
    if (i < N_NODES) rp[i] += part[i >> 8];
    if (i == 0) rp[N_NODES] = N_EDGES;
}

__global__ __launch_bounds__(256) void k_fill(const int* __restrict__ ei,
                                              const int* __restrict__ rp,
                                              const float* __restrict__ dis,
                                              int* __restrict__ cursor,
                                              int* __restrict__ src_csr,
                                              float* __restrict__ norm_csr) {
    int e = blockIdx.x * 256 + threadIdx.x;
    if (e < N_EDGES) {
        int s = ei[e];
        int d = ei[N_EDGES + e];
        int pos = rp[d] + atomicAdd(&cursor[d], 1);
        src_csr[pos] = s;
        norm_csr[pos] = dis[s] * dis[d];
    }
}

// ---------------- graph row pointers from sorted batch ----------------

__global__ __launch_bounds__(256) void k_grp(const int* __restrict__ batch, int* __restrict__ grp) {
    int g = blockIdx.x * 256 + threadIdx.x;
    if (g > N_GRAPHS) return;
    if (g == N_GRAPHS) { grp[g] = N_NODES; return; }
    int lo = 0, hi = N_NODES;
    while (lo < hi) {
        int mid = (lo + hi) >> 1;
        if (batch[mid] < g) lo = mid + 1; else hi = mid;
    }
    grp[g] = lo;
}

// ---------------- W split: WhT/WlT[n][k] bf16 (transposed, truncation split) ----------------

__global__ __launch_bounds__(256) void k_wsplit(const float* __restrict__ W,
                                                unsigned short* __restrict__ WhT,
                                                unsigned short* __restrict__ WlT) {
    int idx = blockIdx.x * 256 + threadIdx.x;   // layer*16384 + k*128 + n
    if (idx >= N_CONV * DIM * DIM) return;
    int layer = idx >> 14;
    int rem = idx & 16383;
    int k = rem >> 7;
    int n = rem & 127;
    float f = W[idx];
    unsigned int u = __float_as_uint(f);
    unsigned int h = u & 0xFFFF0000u;
    float lo = f - __uint_as_float(h);
    int dst = (layer << 14) | (n << 7) | k;
    WhT[dst] = (unsigned short)(h >> 16);
    WlT[dst] = (unsigned short)(__float_as_uint(lo) >> 16);
}

// ---------------- GEMM via MFMA bf16x3: Bb16[N,128] = bf16( A[N,128] @ W ) ----------------
// block: 256 thr = 4 waves x 64 rows = 256 rows. Whole WhT/WlT in 64KB LDS (XOR-swizzled).
// frags (HW-verified r5/6): A row=l&15, k=8*(l>>4)+j; D col=l&15, row=(l>>4)*4+r.

__global__ __launch_bounds__(256, 2) void k_gemm_mfma(const float* __restrict__ Ain,
                                                      const unsigned short* __restrict__ WhT,
                                                      const unsigned short* __restrict__ WlT,
                                                      unsigned short* __restrict__ Cout16) {
    __shared__ unsigned short WL[2 * DIM * DIM];   // 64 KB: [h|l][n][k] swizzled

    int t = threadIdx.x;
#pragma unroll
    for (int it = 0; it < 8; ++it) {
        int idx = it * 256 + t;          // uint4 index (8 bf16 each)
        int n = idx >> 4;
        int kc = idx & 15;
        int byte = n * 256 + kc * 16;
        int swz = byte ^ ((n & 7) << 4);
        *(uint4*)((char*)WL + swz) = ((const uint4*)WhT)[idx];
        *(uint4*)((char*)WL + 32768 + swz) = ((const uint4*)WlT)[idx];
    }
    __syncthreads();

    int w = t >> 6;
    int l = t & 63;
    int lr = l & 15;     // A-row-in-tile / D-col
    int lk = l >> 4;     // k-group
    int row_base = blockIdx.x * 256 + w * 64;

    f32x4 acc[4][8];
#pragma unroll
    for (int m = 0; m < 4; ++m)
#pragma unroll
        for (int nt = 0; nt < 8; ++nt) acc[m][nt] = (f32x4)0.0f;

    const char* WLB = (const char*)WL;
    int wswz = (lr & 7) << 4;    // (n&7)<<4 with n = nt*16+lr

#pragma unroll 1
    for (int kt = 0; kt < 4; ++kt) {
        s16x8 ah[4], al[4];
#pragma unroll
        for (int m = 0; m < 4; ++m) {
            int row = row_base + m * 16 + lr;
            int rc = row < N_NODES ? row : N_NODES - 1;
            const float* ap = Ain + (size_t)rc * DIM + kt * 32 + lk * 8;
            float4 f0 = *(const float4*)ap;
            float4 f1 = *(const float4*)(ap + 4);
            float fs[8] = {f0.x, f0.y, f0.z, f0.w, f1.x, f1.y, f1.z, f1.w};
            union { int i[4]; s16x8 v; } H, L;
#pragma unroll
            for (int d = 0; d < 4; ++d) {
                float a0 = fs[2 * d], a1 = fs[2 * d + 1];
                unsigned int u0 = __float_as_uint(a0), u1 = __float_as_uint(a1);
                unsigned int h0 = u0 & 0xFFFF0000u, h1 = u1 & 0xFFFF0000u;
                float lo0 = a0 - __uint_as_float(h0);
                float lo1 = a1 - __uint_as_float(h1);
                H.i[d] = (int)(h1 | (h0 >> 16));
                L.i[d] = (int)((__float_as_uint(lo1) & 0xFFFF0000u) | (__float_as_uint(lo0) >> 16));
            }
            ah[m] = H.v;
            al[m] = L.v;
        }
#pragma unroll
        for (int nt = 0; nt < 8; ++nt) {
            int nbyte = ((nt * 16 + lr) * 256 + kt * 64 + lk * 16) ^ wswz;
            s16x8 wh = *(const s16x8*)(WLB + nbyte);
            s16x8 wl = *(const s16x8*)(WLB + 32768 + nbyte);
#pragma unroll
            for (int m = 0; m < 4; ++m) {
                acc[m][nt] = __builtin_amdgcn_mfma_f32_16x16x32_bf16(ah[m], wh, acc[m][nt], 0, 0, 0);
                acc[m][nt] = __builtin_amdgcn_mfma_f32_16x16x32_bf16(ah[m], wl, acc[m][nt], 0, 0, 0);
                acc[m][nt] = __builtin_amdgcn_mfma_f32_16x16x32_bf16(al[m], wh, acc[m][nt], 0, 0, 0);
            }
        }
    }

    // store bf16 (RNE)
#pragma unroll
    for (int m = 0; m < 4; ++m)
#pragma unroll
        for (int nt = 0; nt < 8; ++nt)
#pragma unroll
            for (int r = 0; r < 4; ++r) {
                int row = row_base + m * 16 + lk * 4 + r;
                if (row < N_NODES) {
                    unsigned int u = __float_as_uint(acc[m][nt][r]);
                    u += 0x7FFFu + ((u >> 16) & 1u);
                    Cout16[(size_t)row * DIM + nt * 16 + lr] = (unsigned short)(u >> 16);
                }
            }
}

// ---------------- pull aggregation from bf16 rows + bias + relu (fused) ----------------
// 32-lane group per node; lane owns 4 dims (one uint2 = 4 bf16 per row).

__device__ __forceinline__ float4 bf4_to_f4(uint2 u) {
    return make_float4(__uint_as_float(u.x << 16),
                       __uint_as_float(u.x & 0xFFFF0000u),
                       __uint_as_float(u.y << 16),
                       __uint_as_float(u.y & 0xFFFF0000u));
}

__global__ __launch_bounds__(256) void k_gather(const uint2* __restrict__ B2,
                                                const int* __restrict__ rp,
                                                const int* __restrict__ src_csr,
                                                const float* __restrict__ norm_csr,
                                                const float* __restrict__ dis,
                                                const float* __restrict__ bias,
                                                float4* __restrict__ A4) {
    int t = threadIdx.x;
    int n = blockIdx.x * 8 + (t >> 5);      // 100000 / 8 = 12500 blocks exact
    int lane = t & 31;

    float dn = dis[n];
    float self_nrm = dn * dn;
    float4 v = bf4_to_f4(B2[(size_t)n * 32 + lane]);
    float4 acc = make_float4(v.x * self_nrm, v.y * self_nrm, v.z * self_nrm, v.w * self_nrm);

    int beg = rp[n], end = rp[n + 1];
    int e = beg;
    for (; e + 3 < end; e += 4) {
        int s0 = src_csr[e], s1 = src_csr[e + 1], s2 = src_csr[e + 2], s3 = src_csr[e + 3];
        float m0 = norm_csr[e], m1 = norm_csr[e + 1], m2 = norm_csr[e + 2], m3 = norm_csr[e + 3];
        float4 u0 = bf4_to_f4(B2[(size_t)s0 * 32 + lane]);
        float4 u1 = bf4_to_f4(B2[(size_t)s1 * 32 + lane]);
        float4 u2 = bf4_to_f4(B2[(size_t)s2 * 32 + lane]);
        float4 u3 = bf4_to_f4(B2[(size_t)s3 * 32 + lane]);
        acc.x += u0.x * m0 + u1.x * m1 + u2.x * m2 + u3.x * m3;
        acc.y += u0.y * m0 + u1.y * m1 + u2.y * m2 + u3.y * m3;
        acc.z += u0.z * m0 + u1.z * m1 + u2.z * m2 + u3.z * m3;
        acc.w += u0.w * m0 + u1.w * m1 + u2.w * m2 + u3.w * m3;
    }
    for (; e < end; ++e) {
        int s0 = src_csr[e];
        float m0 = norm_csr[e];
        float4 u0 = bf4_to_f4(B2[(size_t)s0 * 32 + lane]);
        acc.x += u0.x * m0; acc.y += u0.y * m0;
        acc.z += u0.z * m0; acc.w += u0.w * m0;
    }

    float4 b = ((const float4*)bias)[lane];
    acc.x = fmaxf(acc.x + b.x, 0.f);
    acc.y = fmaxf(acc.y + b.y, 0.f);
    acc.z = fmaxf(acc.z + b.z, 0.f);
    acc.w = fmaxf(acc.w + b.w, 0.f);
    A4[(size_t)n * 32 + lane] = acc;
}

// ---------------- segmented pooling ----------------

__global__ __launch_bounds__(256) void k_pool_seg(const float4* __restrict__ A4,
                                                  const int* __restrict__ grp,
                                                  float4* __restrict__ means4) {
    __shared__ float4 s[256];
    int g = blockIdx.x;
    int t = threadIdx.x;
    int lane = t & 31;
    int slot = t >> 5;
    int beg = grp[g], end = grp[g + 1];

    float4 acc = make_float4(0.f, 0.f, 0.f, 0.f);
    for (int n = beg + slot; n < end; n += 8) {
        float4 v = A4[(size_t)n * 32 + lane];
        acc.x += v.x; acc.y += v.y; acc.z += v.z; acc.w += v.w;
    }
    s[t] = acc;
    __syncthreads();
    if (t < 32) {
        float4 a = s[t];
#pragma unroll
        for (int i = 1; i < 8; ++i) {
            float4 b = s[t + i * 32];
            a.x += b.x; a.y += b.y; a.z += b.z; a.w += b.w;
        }
        float inv = (end > beg) ? 1.0f / (float)(end - beg) : 0.0f;
        means4[g * 32 + t] = make_float4(a.x * inv, a.y * inv, a.z * inv, a.w * inv);
    }
}

// ---------------- MLP head ----------------

__global__ __launch_bounds__(256) void k_mlp(const float* __restrict__ means,
                                             const float* __restrict__ w1,
                                             const float* __restrict__ b1,
                                             const float* __restrict__ w2,
                                             const float* __restrict__ b2,
                                             float* __restrict__ out) {
    __shared__ float m[DIM];
    __shared__ float red[HIDDEN];
    int g = blockIdx.x;
    int t = threadIdx.x;
    if (t < DIM) m[t] = means[g * DIM + t];
    __syncthreads();
    float h = b1[t];
    for (int c = 0; c < DIM; ++c) h += m[c] * w1[c * HIDDEN + t];
    red[t] = fmaxf(h, 0.f) * w2[t];
    __syncthreads();
    for (int s = HIDDEN / 2; s > 0; s >>= 1) {
        if (t < s) red[t] += red[t + s];
        __syncthreads();
    }
    if (t == 0) out[g] = red[0] + b2[0];
}

// ---------------- launch ----------------

extern "C" void kernel_launch(void* const* d_in, const int* in_sizes, int n_in,
                              void* d_out, int out_size, void* d_ws, size_t ws_size,
                              hipStream_t stream) {
    const float* x      = (const float*)d_in[0];
    const float* conv_w = (const float*)d_in[1];
    const float* conv_b = (const float*)d_in[2];
    const float* w1     = (const float*)d_in[3];
    const float* b1     = (const float*)d_in[4];
    const float* w2     = (const float*)d_in[5];
    const float* b2     = (const float*)d_in[6];
    const int*   ei     = (const int*)d_in[7];
    const int*   batch  = (const int*)d_in[8];
    float* out = (float*)d_out;

    char* ws = (char*)d_ws;
    size_t off = 0;
    auto alloc = [&](size_t bytes) {
        char* p = ws + off;
        off += (bytes + 255) & ~(size_t)255;
        return p;
    };
    float* A              = (float*)alloc((size_t)N_NODES * DIM * 4);          // h buffer, 51.2 MB
    unsigned short* Bb16  = (unsigned short*)alloc((size_t)N_NODES * DIM * 2); // hW bf16, 25.6 MB
    int*   cnt      = (int*)alloc((size_t)N_NODES * 4);
    float* dis      = (float*)alloc((size_t)N_NODES * 4);
    int*   rp       = (int*)alloc((size_t)(N_NODES + 1) * 4);
    int*   part     = (int*)alloc((size_t)NB_SCAN * 4);
    int*   src_csr  = (int*)alloc((size_t)N_EDGES * 4);
    float* norm_csr = (float*)alloc((size_t)N_EDGES * 4);
    int*   grp      = (int*)alloc((size_t)(N_GRAPHS + 1) * 4);
    float* means    = (float*)alloc((size_t)N_GRAPHS * DIM * 4);
    unsigned short* WhT = (unsigned short*)alloc((size_t)N_CONV * DIM * DIM * 2);
    unsigned short* WlT = (unsigned short*)alloc((size_t)N_CONV * DIM * DIM * 2);
    (void)ws_size; (void)in_sizes; (void)n_in; (void)out_size;

    // --- CSR build + W split (once per call) ---
    hipMemsetAsync(cnt, 0, (size_t)N_NODES * 4, stream);
    k_hist<<<(N_EDGES + 255) / 256, 256, 0, stream>>>(ei, cnt);
    k_dis<<<(N_NODES + 255) / 256, 256, 0, stream>>>(cnt, dis);
    k_scan1<<<NB_SCAN, 256, 0, stream>>>(cnt, rp, part);
    k_scan2<<<1, 512, 0, stream>>>(part);
    k_scan3<<<NB_SCAN, 256, 0, stream>>>(rp, part);
    hipMemsetAsync(cnt, 0, (size_t)N_NODES * 4, stream);
    k_fill<<<(N_EDGES + 255) / 256, 256, 0, stream>>>(ei, rp, dis, cnt, src_csr, norm_csr);
    k_grp<<<(N_GRAPHS + 256) / 256, 256, 0, stream>>>(batch, grp);
    k_wsplit<<<(N_CONV * DIM * DIM) / 256, 256, 0, stream>>>(conv_w, WhT, WlT);

    // --- conv layers: gemm (fp32 h -> bf16 hW), gather (bf16 rows -> fp32 h) ---
    const float* cur = x;
    for (int L = 0; L < N_CONV; ++L) {
        k_gemm_mfma<<<(N_NODES + 255) / 256, 256, 0, stream>>>(
            cur, WhT + L * DIM * DIM, WlT + L * DIM * DIM, Bb16);
        k_gather<<<N_NODES / 8, 256, 0, stream>>>((const uint2*)Bb16, rp, src_csr, norm_csr,
                                                  dis, conv_b + L * DIM, (float4*)A);
        cur = A;
    }

    // --- pool + MLP ---
    k_pool_seg<<<N_GRAPHS, 256, 0, stream>>>((const float4*)A, grp, (float4*)means);
    k_mlp<<<N_GRAPHS, 256, 0, stream>>>(means, w1, b1, w2, b2, out);
}

// Round 11
// 402.369 us; speedup vs baseline: 1.4432x; 1.0819x over previous
//
#include <hip/hip_runtime.h>

#define N_NODES 100000
#define N_EDGES 600000
#define N_GRAPHS 2000
#define DIM 128
#define HIDDEN 256
#define N_CONV 4
#define NB_SCAN ((N_NODES + 255) / 256)   // 391

typedef short s16x8 __attribute__((ext_vector_type(8)));
typedef float f32x4 __attribute__((ext_vector_type(4)));

__device__ __forceinline__ unsigned int bf16_rne(float f) {
    unsigned int u = __float_as_uint(f);
    u += 0x7FFFu + ((u >> 16) & 1u);
    return u >> 16;
}

__device__ __forceinline__ float4 bf4_to_f4(uint2 u) {
    return make_float4(__uint_as_float(u.x << 16),
                       __uint_as_float(u.x & 0xFFFF0000u),
                       __uint_as_float(u.y << 16),
                       __uint_as_float(u.y & 0xFFFF0000u));
}

// ---------------- CSR build ----------------

__global__ __launch_bounds__(256) void k_hist(const int* __restrict__ ei, int* __restrict__ cnt) {
    int e = blockIdx.x * 256 + threadIdx.x;
    if (e < N_EDGES) atomicAdd(&cnt[ei[N_EDGES + e]], 1);
}

__global__ __launch_bounds__(256) void k_dis(const int* __restrict__ cnt, float* __restrict__ dis) {
    int i = blockIdx.x * 256 + threadIdx.x;
    if (i < N_NODES) dis[i] = rsqrtf(1.0f + (float)cnt[i]);
}

__global__ __launch_bounds__(256) void k_scan1(const int* __restrict__ cnt,
                                               int* __restrict__ rp,
                                               int* __restrict__ part) {
    __shared__ int s[256];
    int t = threadIdx.x;
    int i = blockIdx.x * 256 + t;
    int v = (i < N_NODES) ? cnt[i] : 0;
    s[t] = v;
    __syncthreads();
    for (int o = 1; o < 256; o <<= 1) {
        int x = (t >= o) ? s[t - o] : 0;
        __syncthreads();
        s[t] += x;
        __syncthreads();
    }
    if (i < N_NODES) rp[i] = s[t] - v;
    if (t == 255) part[blockIdx.x] = s[255];
}

__global__ __launch_bounds__(512) void k_scan2(int* __restrict__ part) {
    __shared__ int s[512];
    int t = threadIdx.x;
    int v = (t < NB_SCAN) ? part[t] : 0;
    s[t] = v;
    __syncthreads();
    for (int o = 1; o < 512; o <<= 1) {
        int x = (t >= o) ? s[t - o] : 0;
        __syncthreads();
        s[t] += x;
        __syncthreads();
    }
    if (t < NB_SCAN) part[t] = s[t] - v;
}

__global__ __launch_bounds__(256) void k_scan3(int* __restrict__ rp, const int* __restrict__ part) {
    int i = blockIdx.x * 256 + threadIdx.x;
    if (i < N_NODES) rp[i] += part[i >> 8];
    if (i == 0) rp[N_NODES] = N_EDGES;
}

__global__ __launch_bounds__(256) void k_fill(const int* __restrict__ ei,
                                              const int* __restrict__ rp,
                                              const float* __restrict__ dis,
                                              int* __restrict__ cursor,
                                              int* __restrict__ src_csr,
                                              float* __restrict__ norm_csr) {
    int e = blockIdx.x * 256 + threadIdx.x;
    if (e < N_EDGES) {
        int s = ei[e];
        int d = ei[N_EDGES + e];
        int pos = rp[d] + atomicAdd(&cursor[d], 1);
        src_csr[pos] = s;
        norm_csr[pos] = dis[s] * dis[d];
    }
}

// ---------------- graph row pointers from sorted batch ----------------

__global__ __launch_bounds__(256) void k_grp(const int* __restrict__ batch, int* __restrict__ grp) {
    int g = blockIdx.x * 256 + threadIdx.x;
    if (g > N_GRAPHS) return;
    if (g == N_GRAPHS) { grp[g] = N_NODES; return; }
    int lo = 0, hi = N_NODES;
    while (lo < hi) {
        int mid = (lo + hi) >> 1;
        if (batch[mid] < g) lo = mid + 1; else hi = mid;
    }
    grp[g] = lo;
}

// ---------------- W split: WhT/WlT[n][k] bf16 (transposed, truncation split) ----------------

__global__ __launch_bounds__(256) void k_wsplit(const float* __restrict__ W,
                                                unsigned short* __restrict__ WhT,
                                                unsigned short* __restrict__ WlT) {
    int idx = blockIdx.x * 256 + threadIdx.x;   // layer*16384 + k*128 + n
    if (idx >= N_CONV * DIM * DIM) return;
    int layer = idx >> 14;
    int rem = idx & 16383;
    int k = rem >> 7;
    int n = rem & 127;
    float f = W[idx];
    unsigned int u = __float_as_uint(f);
    unsigned int h = u & 0xFFFF0000u;
    float lo = f - __uint_as_float(h);
    int dst = (layer << 14) | (n << 7) | k;
    WhT[dst] = (unsigned short)(h >> 16);
    WlT[dst] = (unsigned short)(__float_as_uint(lo) >> 16);
}

// ---------------- GEMM L0 (fp32 A, bf16x3): Bb16 = bf16( x @ W ) ----------------
// 256 thr = 4 waves x 64 rows. Whole WhT/WlT in 64KB LDS (XOR-swizzled).
// frags (HW-verified r5/6): A row=l&15, k=8*(l>>4)+j; D col=l&15, row=(l>>4)*4+r.

__global__ __launch_bounds__(256, 2) void k_gemm_f32(const float* __restrict__ Ain,
                                                     const unsigned short* __restrict__ WhT,
                                                     const unsigned short* __restrict__ WlT,
                                                     unsigned short* __restrict__ Cout16) {
    __shared__ unsigned short WL[2 * DIM * DIM];   // 64 KB

    int t = threadIdx.x;
#pragma unroll
    for (int it = 0; it < 8; ++it) {
        int idx = it * 256 + t;
        int n = idx >> 4;
        int kc = idx & 15;
        int byte = n * 256 + kc * 16;
        int swz = byte ^ ((n & 7) << 4);
        *(uint4*)((char*)WL + swz) = ((const uint4*)WhT)[idx];
        *(uint4*)((char*)WL + 32768 + swz) = ((const uint4*)WlT)[idx];
    }
    __syncthreads();

    int w = t >> 6;
    int l = t & 63;
    int lr = l & 15;
    int lk = l >> 4;
    int row_base = blockIdx.x * 256 + w * 64;

    f32x4 acc[4][8];
#pragma unroll
    for (int m = 0; m < 4; ++m)
#pragma unroll
        for (int nt = 0; nt < 8; ++nt) acc[m][nt] = (f32x4)0.0f;

    const char* WLB = (const char*)WL;
    int wswz = (lr & 7) << 4;

#pragma unroll 1
    for (int kt = 0; kt < 4; ++kt) {
        s16x8 ah[4], al[4];
#pragma unroll
        for (int m = 0; m < 4; ++m) {
            int row = row_base + m * 16 + lr;
            int rc = row < N_NODES ? row : N_NODES - 1;
            const float* ap = Ain + (size_t)rc * DIM + kt * 32 + lk * 8;
            float4 f0 = *(const float4*)ap;
            float4 f1 = *(const float4*)(ap + 4);
            float fs[8] = {f0.x, f0.y, f0.z, f0.w, f1.x, f1.y, f1.z, f1.w};
            union { int i[4]; s16x8 v; } H, L;
#pragma unroll
            for (int d = 0; d < 4; ++d) {
                float a0 = fs[2 * d], a1 = fs[2 * d + 1];
                unsigned int u0 = __float_as_uint(a0), u1 = __float_as_uint(a1);
                unsigned int h0 = u0 & 0xFFFF0000u, h1 = u1 & 0xFFFF0000u;
                float lo0 = a0 - __uint_as_float(h0);
                float lo1 = a1 - __uint_as_float(h1);
                H.i[d] = (int)(h1 | (h0 >> 16));
                L.i[d] = (int)((__float_as_uint(lo1) & 0xFFFF0000u) | (__float_as_uint(lo0) >> 16));
            }
            ah[m] = H.v;
            al[m] = L.v;
        }
#pragma unroll
        for (int nt = 0; nt < 8; ++nt) {
            int nbyte = ((nt * 16 + lr) * 256 + kt * 64 + lk * 16) ^ wswz;
            s16x8 wh = *(const s16x8*)(WLB + nbyte);
            s16x8 wl = *(const s16x8*)(WLB + 32768 + nbyte);
#pragma unroll
            for (int m = 0; m < 4; ++m) {
                acc[m][nt] = __builtin_amdgcn_mfma_f32_16x16x32_bf16(ah[m], wh, acc[m][nt], 0, 0, 0);
                acc[m][nt] = __builtin_amdgcn_mfma_f32_16x16x32_bf16(ah[m], wl, acc[m][nt], 0, 0, 0);
                acc[m][nt] = __builtin_amdgcn_mfma_f32_16x16x32_bf16(al[m], wh, acc[m][nt], 0, 0, 0);
            }
        }
    }

#pragma unroll
    for (int m = 0; m < 4; ++m)
#pragma unroll
        for (int nt = 0; nt < 8; ++nt)
#pragma unroll
            for (int r = 0; r < 4; ++r) {
                int row = row_base + m * 16 + lk * 4 + r;
                if (row < N_NODES)
                    Cout16[(size_t)row * DIM + nt * 16 + lr] =
                        (unsigned short)bf16_rne(acc[m][nt][r]);
            }
}

// ---------------- GEMM L1-3 (bf16 A exact, 2-term): Bb16 = bf16( h @ W ) ----------------

__global__ __launch_bounds__(256, 2) void k_gemm_b16(const unsigned short* __restrict__ Ain16,
                                                     const unsigned short* __restrict__ WhT,
                                                     const unsigned short* __restrict__ WlT,
                                                     unsigned short* __restrict__ Cout16) {
    __shared__ unsigned short WL[2 * DIM * DIM];   // 64 KB

    int t = threadIdx.x;
#pragma unroll
    for (int it = 0; it < 8; ++it) {
        int idx = it * 256 + t;
        int n = idx >> 4;
        int kc = idx & 15;
        int byte = n * 256 + kc * 16;
        int swz = byte ^ ((n & 7) << 4);
        *(uint4*)((char*)WL + swz) = ((const uint4*)WhT)[idx];
        *(uint4*)((char*)WL + 32768 + swz) = ((const uint4*)WlT)[idx];
    }
    __syncthreads();

    int w = t >> 6;
    int l = t & 63;
    int lr = l & 15;
    int lk = l >> 4;
    int row_base = blockIdx.x * 256 + w * 64;

    f32x4 acc[4][8];
#pragma unroll
    for (int m = 0; m < 4; ++m)
#pragma unroll
        for (int nt = 0; nt < 8; ++nt) acc[m][nt] = (f32x4)0.0f;

    const char* WLB = (const char*)WL;
    int wswz = (lr & 7) << 4;

#pragma unroll 1
    for (int kt = 0; kt < 4; ++kt) {
        s16x8 a[4];
#pragma unroll
        for (int m = 0; m < 4; ++m) {
            int row = row_base + m * 16 + lr;
            int rc = row < N_NODES ? row : N_NODES - 1;
            a[m] = *(const s16x8*)(Ain16 + (size_t)rc * DIM + kt * 32 + lk * 8);
        }
#pragma unroll
        for (int nt = 0; nt < 8; ++nt) {
            int nbyte = ((nt * 16 + lr) * 256 + kt * 64 + lk * 16) ^ wswz;
            s16x8 wh = *(const s16x8*)(WLB + nbyte);
            s16x8 wl = *(const s16x8*)(WLB + 32768 + nbyte);
#pragma unroll
            for (int m = 0; m < 4; ++m) {
                acc[m][nt] = __builtin_amdgcn_mfma_f32_16x16x32_bf16(a[m], wh, acc[m][nt], 0, 0, 0);
                acc[m][nt] = __builtin_amdgcn_mfma_f32_16x16x32_bf16(a[m], wl, acc[m][nt], 0, 0, 0);
            }
        }
    }

#pragma unroll
    for (int m = 0; m < 4; ++m)
#pragma unroll
        for (int nt = 0; nt < 8; ++nt)
#pragma unroll
            for (int r = 0; r < 4; ++r) {
                int row = row_base + m * 16 + lk * 4 + r;
                if (row < N_NODES)
                    Cout16[(size_t)row * DIM + nt * 16 + lr] =
                        (unsigned short)bf16_rne(acc[m][nt][r]);
            }
}

// ---------------- pull aggregation (bf16 in, bf16 out) + bias + relu ----------------
// 32-lane group per node; lane owns 4 dims (uint2 = 4 bf16).

__global__ __launch_bounds__(256) void k_gather(const uint2* __restrict__ B2,
                                                const int* __restrict__ rp,
                                                const int* __restrict__ src_csr,
                                                const float* __restrict__ norm_csr,
                                                const float* __restrict__ dis,
                                                const float* __restrict__ bias,
                                                uint2* __restrict__ Aout2) {
    int t = threadIdx.x;
    int n = blockIdx.x * 8 + (t >> 5);      // 100000 / 8 = 12500 blocks exact
    int lane = t & 31;

    float dn = dis[n];
    float self_nrm = dn * dn;
    float4 v = bf4_to_f4(B2[(size_t)n * 32 + lane]);
    float4 acc = make_float4(v.x * self_nrm, v.y * self_nrm, v.z * self_nrm, v.w * self_nrm);

    int beg = rp[n], end = rp[n + 1];
    int e = beg;
    for (; e + 3 < end; e += 4) {
        int s0 = src_csr[e], s1 = src_csr[e + 1], s2 = src_csr[e + 2], s3 = src_csr[e + 3];
        float m0 = norm_csr[e], m1 = norm_csr[e + 1], m2 = norm_csr[e + 2], m3 = norm_csr[e + 3];
        float4 u0 = bf4_to_f4(B2[(size_t)s0 * 32 + lane]);
        float4 u1 = bf4_to_f4(B2[(size_t)s1 * 32 + lane]);
        float4 u2 = bf4_to_f4(B2[(size_t)s2 * 32 + lane]);
        float4 u3 = bf4_to_f4(B2[(size_t)s3 * 32 + lane]);
        acc.x += u0.x * m0 + u1.x * m1 + u2.x * m2 + u3.x * m3;
        acc.y += u0.y * m0 + u1.y * m1 + u2.y * m2 + u3.y * m3;
        acc.z += u0.z * m0 + u1.z * m1 + u2.z * m2 + u3.z * m3;
        acc.w += u0.w * m0 + u1.w * m1 + u2.w * m2 + u3.w * m3;
    }
    for (; e < end; ++e) {
        int s0 = src_csr[e];
        float m0 = norm_csr[e];
        float4 u0 = bf4_to_f4(B2[(size_t)s0 * 32 + lane]);
        acc.x += u0.x * m0; acc.y += u0.y * m0;
        acc.z += u0.z * m0; acc.w += u0.w * m0;
    }

    float4 b = ((const float4*)bias)[lane];
    acc.x = fmaxf(acc.x + b.x, 0.f);
    acc.y = fmaxf(acc.y + b.y, 0.f);
    acc.z = fmaxf(acc.z + b.z, 0.f);
    acc.w = fmaxf(acc.w + b.w, 0.f);

    uint2 o;
    o.x = bf16_rne(acc.x) | (bf16_rne(acc.y) << 16);
    o.y = bf16_rne(acc.z) | (bf16_rne(acc.w) << 16);
    Aout2[(size_t)n * 32 + lane] = o;
}

// ---------------- segmented pooling (bf16 in, fp32 means out) ----------------

__global__ __launch_bounds__(256) void k_pool_seg(const uint2* __restrict__ A2,
                                                  const int* __restrict__ grp,
                                                  float4* __restrict__ means4) {
    __shared__ float4 s[256];
    int g = blockIdx.x;
    int t = threadIdx.x;
    int lane = t & 31;
    int slot = t >> 5;
    int beg = grp[g], end = grp[g + 1];

    float4 acc = make_float4(0.f, 0.f, 0.f, 0.f);
    for (int n = beg + slot; n < end; n += 8) {
        float4 v = bf4_to_f4(A2[(size_t)n * 32 + lane]);
        acc.x += v.x; acc.y += v.y; acc.z += v.z; acc.w += v.w;
    }
    s[t] = acc;
    __syncthreads();
    if (t < 32) {
        float4 a = s[t];
#pragma unroll
        for (int i = 1; i < 8; ++i) {
            float4 b = s[t + i * 32];
            a.x += b.x; a.y += b.y; a.z += b.z; a.w += b.w;
        }
        float inv = (end > beg) ? 1.0f / (float)(end - beg) : 0.0f;
        means4[g * 32 + t] = make_float4(a.x * inv, a.y * inv, a.z * inv, a.w * inv);
    }
}

// ---------------- MLP head ----------------

__global__ __launch_bounds__(256) void k_mlp(const float* __restrict__ means,
                                             const float* __restrict__ w1,
                                             const float* __restrict__ b1,
                                             const float* __restrict__ w2,
                                             const float* __restrict__ b2,
                                             float* __restrict__ out) {
    __shared__ float m[DIM];
    __shared__ float red[HIDDEN];
    int g = blockIdx.x;
    int t = threadIdx.x;
    if (t < DIM) m[t] = means[g * DIM + t];
    __syncthreads();
    float h = b1[t];
    for (int c = 0; c < DIM; ++c) h += m[c] * w1[c * HIDDEN + t];
    red[t] = fmaxf(h, 0.f) * w2[t];
    __syncthreads();
    for (int s = HIDDEN / 2; s > 0; s >>= 1) {
        if (t < s) red[t] += red[t + s];
        __syncthreads();
    }
    if (t == 0) out[g] = red[0] + b2[0];
}

// ---------------- launch ----------------

extern "C" void kernel_launch(void* const* d_in, const int* in_sizes, int n_in,
                              void* d_out, int out_size, void* d_ws, size_t ws_size,
                              hipStream_t stream) {
    const float* x      = (const float*)d_in[0];
    const float* conv_w = (const float*)d_in[1];
    const float* conv_b = (const float*)d_in[2];
    const float* w1     = (const float*)d_in[3];
    const float* b1     = (const float*)d_in[4];
    const float* w2     = (const float*)d_in[5];
    const float* b2     = (const float*)d_in[6];
    const int*   ei     = (const int*)d_in[7];
    const int*   batch  = (const int*)d_in[8];
    float* out = (float*)d_out;

    char* ws = (char*)d_ws;
    size_t off = 0;
    auto alloc = [&](size_t bytes) {
        char* p = ws + off;
        off += (bytes + 255) & ~(size_t)255;
        return p;
    };
    unsigned short* A16   = (unsigned short*)alloc((size_t)N_NODES * DIM * 2); // h bf16, 25.6 MB
    unsigned short* Bb16  = (unsigned short*)alloc((size_t)N_NODES * DIM * 2); // hW bf16, 25.6 MB
    int*   cnt      = (int*)alloc((size_t)N_NODES * 4);
    float* dis      = (float*)alloc((size_t)N_NODES * 4);
    int*   rp       = (int*)alloc((size_t)(N_NODES + 1) * 4);
    int*   part     = (int*)alloc((size_t)NB_SCAN * 4);
    int*   src_csr  = (int*)alloc((size_t)N_EDGES * 4);
    float* norm_csr = (float*)alloc((size_t)N_EDGES * 4);
    int*   grp      = (int*)alloc((size_t)(N_GRAPHS + 1) * 4);
    float* means    = (float*)alloc((size_t)N_GRAPHS * DIM * 4);
    unsigned short* WhT = (unsigned short*)alloc((size_t)N_CONV * DIM * DIM * 2);
    unsigned short* WlT = (unsigned short*)alloc((size_t)N_CONV * DIM * DIM * 2);
    (void)ws_size; (void)in_sizes; (void)n_in; (void)out_size;

    // --- CSR build + W split (once per call) ---
    hipMemsetAsync(cnt, 0, (size_t)N_NODES * 4, stream);
    k_hist<<<(N_EDGES + 255) / 256, 256, 0, stream>>>(ei, cnt);
    k_dis<<<(N_NODES + 255) / 256, 256, 0, stream>>>(cnt, dis);
    k_scan1<<<NB_SCAN, 256, 0, stream>>>(cnt, rp, part);
    k_scan2<<<1, 512, 0, stream>>>(part);
    k_scan3<<<NB_SCAN, 256, 0, stream>>>(rp, part);
    hipMemsetAsync(cnt, 0, (size_t)N_NODES * 4, stream);
    k_fill<<<(N_EDGES + 255) / 256, 256, 0, stream>>>(ei, rp, dis, cnt, src_csr, norm_csr);
    k_grp<<<(N_GRAPHS + 256) / 256, 256, 0, stream>>>(batch, grp);
    k_wsplit<<<(N_CONV * DIM * DIM) / 256, 256, 0, stream>>>(conv_w, WhT, WlT);

    // --- conv layers ---
    // L0: fp32 x -> bf16 Bb ; gather bf16 -> bf16 A ; L1-3: bf16 A -> bf16 Bb
    k_gemm_f32<<<(N_NODES + 255) / 256, 256, 0, stream>>>(x, WhT, WlT, Bb16);
    k_gather<<<N_NODES / 8, 256, 0, stream>>>((const uint2*)Bb16, rp, src_csr, norm_csr,
                                              dis, conv_b, (uint2*)A16);
    for (int L = 1; L < N_CONV; ++L) {
        k_gemm_b16<<<(N_NODES + 255) / 256, 256, 0, stream>>>(
            A16, WhT + L * DIM * DIM, WlT + L * DIM * DIM, Bb16);
        k_gather<<<N_NODES / 8, 256, 0, stream>>>((const uint2*)Bb16, rp, src_csr, norm_csr,
                                                  dis, conv_b + L * DIM, (uint2*)A16);
    }

    // --- pool + MLP ---
    k_pool_seg<<<N_GRAPHS, 256, 0, stream>>>((const uint2*)A16, grp, (float4*)means);
    k_mlp<<<N_GRAPHS, 256, 0, stream>>>(means, w1, b1, w2, b2, out);
}